// Round 1
// baseline (560.463 us; speedup 1.0000x reference)
//
#include <hip/hip_runtime.h>

// Problem geometry
constexpr int HWSZ = 512 * 512;          // pixels per image plane (2^18)
constexpr int NPIX = 8 * HWSZ;           // 2,097,152 total pixels
constexpr float EPS = 1e-5f;

// Workspace layout (float offsets)
constexpr int OFF_W1  = 0;       // 128 x float4  (w1*inv, b1fold)      -> 512
constexpr int OFF_W2T = 512;     // [128][64] w2 transposed, BN-folded  -> 8192
constexpr int OFF_B2  = 8704;    // 64
constexpr int OFF_W3T = 8768;    // [64][32]                            -> 2048
constexpr int OFF_B3  = 10816;   // 32
constexpr int OFF_W4T = 10848;   // [32][16]                            -> 512
constexpr int OFF_B4  = 11360;   // 16
constexpr int OFF_WH  = 11376;   // 16
constexpr int OFF_BH  = 11392;   // 1
// total 11393 floats = ~45.6 KB of d_ws

__global__ void fold_weights(
    const float* __restrict__ w1, const float* __restrict__ g1, const float* __restrict__ b1,
    const float* __restrict__ m1, const float* __restrict__ v1,
    const float* __restrict__ w2, const float* __restrict__ g2, const float* __restrict__ b2,
    const float* __restrict__ m2, const float* __restrict__ v2,
    const float* __restrict__ w3, const float* __restrict__ g3, const float* __restrict__ b3,
    const float* __restrict__ m3, const float* __restrict__ v3,
    const float* __restrict__ w4, const float* __restrict__ g4, const float* __restrict__ b4,
    const float* __restrict__ m4, const float* __restrict__ v4,
    const float* __restrict__ wh, const float* __restrict__ bh,
    float* __restrict__ ws)
{
    const int t = threadIdx.x;  // 256 threads, single block

    // Layer 1: pack per-input-channel-of-layer2 rows: {w0,w1,w2,bias} * inv
    for (int o = t; o < 128; o += 256) {
        float inv = g1[o] / sqrtf(v1[o] + EPS);
        ws[OFF_W1 + 4*o + 0] = w1[3*o + 0] * inv;
        ws[OFF_W1 + 4*o + 1] = w1[3*o + 1] * inv;
        ws[OFF_W1 + 4*o + 2] = w1[3*o + 2] * inv;
        ws[OFF_W1 + 4*o + 3] = b1[o] - m1[o] * inv;
    }
    // Layer 2 transposed: w2t[c][o] = w2[o][c] * inv2[o]
    for (int i = t; i < 128 * 64; i += 256) {
        int c = i >> 6, o = i & 63;
        float inv = g2[o] / sqrtf(v2[o] + EPS);
        ws[OFF_W2T + i] = w2[o * 128 + c] * inv;
    }
    for (int o = t; o < 64; o += 256) {
        float inv = g2[o] / sqrtf(v2[o] + EPS);
        ws[OFF_B2 + o] = b2[o] - m2[o] * inv;
    }
    // Layer 3 transposed: w3t[c][o] = w3[o][c] * inv3[o]
    for (int i = t; i < 64 * 32; i += 256) {
        int c = i >> 5, o = i & 31;
        float inv = g3[o] / sqrtf(v3[o] + EPS);
        ws[OFF_W3T + i] = w3[o * 64 + c] * inv;
    }
    for (int o = t; o < 32; o += 256) {
        float inv = g3[o] / sqrtf(v3[o] + EPS);
        ws[OFF_B3 + o] = b3[o] - m3[o] * inv;
    }
    // Layer 4 transposed: w4t[c][o] = w4[o][c] * inv4[o]
    for (int i = t; i < 32 * 16; i += 256) {
        int c = i >> 4, o = i & 15;
        float inv = g4[o] / sqrtf(v4[o] + EPS);
        ws[OFF_W4T + i] = w4[o * 32 + c] * inv;
    }
    for (int o = t; o < 16; o += 256) {
        float inv = g4[o] / sqrtf(v4[o] + EPS);
        ws[OFF_B4 + o] = b4[o] - m4[o] * inv;
    }
    // Head
    if (t < 16) ws[OFF_WH + t] = wh[t];
    if (t == 0) ws[OFF_BH] = bh[0];
}

__global__ __launch_bounds__(256) void mlp_fused(
    const float* __restrict__ x, const float* __restrict__ ws, float* __restrict__ out)
{
    const int q = blockIdx.x * 256 + threadIdx.x;
    if (q >= NPIX) return;
    const int n = q >> 18;              // image index (HW = 2^18)
    const int p = q & (HWSZ - 1);       // pixel within plane

    const float* xb = x + (size_t)n * 3 * HWSZ + p;
    const float x0 = xb[0];
    const float x1 = xb[HWSZ];
    const float x2 = xb[2 * HWSZ];

    const float4* __restrict__ w1f = (const float4*)(ws + OFF_W1);
    const float*  __restrict__ w2t = ws + OFF_W2T;
    const float*  __restrict__ b2f = ws + OFF_B2;
    const float*  __restrict__ w3t = ws + OFF_W3T;
    const float*  __restrict__ b3f = ws + OFF_B3;
    const float*  __restrict__ w4t = ws + OFF_W4T;
    const float*  __restrict__ b4f = ws + OFF_B4;
    const float*  __restrict__ whf = ws + OFF_WH;

    // ---- Layers 1+2 fused (outer-product streaming; h1 never materialized) ----
    float acc2[64];
    #pragma unroll
    for (int o = 0; o < 64; ++o) acc2[o] = b2f[o];

    #pragma unroll 2
    for (int c = 0; c < 128; ++c) {
        const float4 wv = w1f[c];  // uniform -> scalar load
        float h = fmaf(wv.x, x0, fmaf(wv.y, x1, fmaf(wv.z, x2, wv.w)));
        h = fmaxf(h, 0.0f);
        const float* wr = w2t + c * 64;
        #pragma unroll
        for (int o = 0; o < 64; ++o) acc2[o] = fmaf(wr[o], h, acc2[o]);
    }

    // ---- Layer 3 (fully unrolled; relu folded into reads of acc2) ----
    float acc3[32];
    #pragma unroll
    for (int o = 0; o < 32; ++o) acc3[o] = b3f[o];
    #pragma unroll
    for (int c = 0; c < 64; ++c) {
        const float h = fmaxf(acc2[c], 0.0f);
        const float* wr = w3t + c * 32;
        #pragma unroll
        for (int o = 0; o < 32; ++o) acc3[o] = fmaf(wr[o], h, acc3[o]);
    }

    // ---- Layer 4 ----
    float acc4[16];
    #pragma unroll
    for (int o = 0; o < 16; ++o) acc4[o] = b4f[o];
    #pragma unroll
    for (int c = 0; c < 32; ++c) {
        const float h = fmaxf(acc3[c], 0.0f);
        const float* wr = w4t + c * 16;
        #pragma unroll
        for (int o = 0; o < 16; ++o) acc4[o] = fmaf(wr[o], h, acc4[o]);
    }

    // ---- Head (no relu on output) ----
    float r = ws[OFF_BH];
    #pragma unroll
    for (int c = 0; c < 16; ++c) r = fmaf(whf[c], fmaxf(acc4[c], 0.0f), r);

    out[q] = r;
}

extern "C" void kernel_launch(void* const* d_in, const int* in_sizes, int n_in,
                              void* d_out, int out_size, void* d_ws, size_t ws_size,
                              hipStream_t stream) {
    const float* x  = (const float*)d_in[0];
    const float* w1 = (const float*)d_in[1];
    const float* g1 = (const float*)d_in[2];
    const float* b1 = (const float*)d_in[3];
    const float* m1 = (const float*)d_in[4];
    const float* v1 = (const float*)d_in[5];
    const float* w2 = (const float*)d_in[6];
    const float* g2 = (const float*)d_in[7];
    const float* b2 = (const float*)d_in[8];
    const float* m2 = (const float*)d_in[9];
    const float* v2 = (const float*)d_in[10];
    const float* w3 = (const float*)d_in[11];
    const float* g3 = (const float*)d_in[12];
    const float* b3 = (const float*)d_in[13];
    const float* m3 = (const float*)d_in[14];
    const float* v3 = (const float*)d_in[15];
    const float* w4 = (const float*)d_in[16];
    const float* g4 = (const float*)d_in[17];
    const float* b4 = (const float*)d_in[18];
    const float* m4 = (const float*)d_in[19];
    const float* v4 = (const float*)d_in[20];
    const float* wh = (const float*)d_in[21];
    const float* bh = (const float*)d_in[22];

    float* ws = (float*)d_ws;
    float* out = (float*)d_out;

    fold_weights<<<1, 256, 0, stream>>>(w1, g1, b1, m1, v1,
                                        w2, g2, b2, m2, v2,
                                        w3, g3, b3, m3, v3,
                                        w4, g4, b4, m4, v4,
                                        wh, bh, ws);

    mlp_fused<<<NPIX / 256, 256, 0, stream>>>(x, ws, out);
}

// Round 9
// 179.181 us; speedup vs baseline: 3.1279x; 3.1279x over previous
//
#include <hip/hip_runtime.h>

// ---------------- geometry ----------------
constexpr int HWSZ = 512 * 512;          // 2^18 pixels per plane
constexpr int NPIX = 8 * HWSZ;           // 2,097,152
constexpr float EPS = 1e-5f;
constexpr int ITERS = 16;                // pixel tiles (32 px) per wave
constexpr int GRID  = 1024;              // blocks of 256 (4 waves): 1024*4*16*32 = NPIX

// folded fp16 weight matrices in ws (f16-unit offsets); K includes bias col + pad
constexpr int S1 = 16, S2 = 144, S3 = 80, S4 = 48;   // row strides (f16)
constexpr int OFF_W1 = 0;                 // [128][16]  cols: w0,w1,w2,bias,0...
constexpr int OFF_W2 = 2048;              // [64][144]  cols 0-127 w, 128 bias, pad
constexpr int OFF_W3 = 11264;             // [32][80]   cols 0-63 w, 64 bias, pad
constexpr int OFF_W4 = 13824;             // [32][48]   rows 0-15 real, 16-31 zero
constexpr int F16_TOTAL = 15360;
constexpr int OFF_WH_F32 = F16_TOTAL / 2; // float index into ws: wh[16]
constexpr int OFF_BH_F32 = OFF_WH_F32 + 16;

typedef _Float16 half8  __attribute__((ext_vector_type(8)));
typedef _Float16 half2t __attribute__((ext_vector_type(2)));
typedef float    f32x16 __attribute__((ext_vector_type(16)));
typedef unsigned int uint4t __attribute__((ext_vector_type(4)));

#define MFMA32(a, b, c) __builtin_amdgcn_mfma_f32_32x32x16_f16((a), (b), (c), 0, 0, 0)

// -------------- weight fold/pack kernel --------------
__global__ void fold_weights(
    const float* __restrict__ w1, const float* __restrict__ g1, const float* __restrict__ b1,
    const float* __restrict__ m1, const float* __restrict__ v1,
    const float* __restrict__ w2, const float* __restrict__ g2, const float* __restrict__ b2,
    const float* __restrict__ m2, const float* __restrict__ v2,
    const float* __restrict__ w3, const float* __restrict__ g3, const float* __restrict__ b3,
    const float* __restrict__ m3, const float* __restrict__ v3,
    const float* __restrict__ w4, const float* __restrict__ g4, const float* __restrict__ b4,
    const float* __restrict__ m4, const float* __restrict__ v4,
    const float* __restrict__ wh, const float* __restrict__ bh,
    void* __restrict__ wsv)
{
    _Float16* wsh = (_Float16*)wsv;
    float*    wsf = (float*)wsv;
    int idx = blockIdx.x * 256 + threadIdx.x;   // grid covers all elements in one pass

    if (idx < 2048) {                    // W1 [128][16]
        int co = idx >> 4, k = idx & 15;
        float inv = g1[co] / sqrtf(v1[co] + EPS);
        float val = (k < 3) ? w1[co * 3 + k] * inv
                  : (k == 3) ? (b1[co] - m1[co] * inv) : 0.0f;
        wsh[OFF_W1 + idx] = (_Float16)val;
    } else if (idx < 11264) {            // W2 [64][144]
        int i = idx - 2048;
        int co = i / S2, k = i - co * S2;
        float inv = g2[co] / sqrtf(v2[co] + EPS);
        float val = (k < 128) ? w2[co * 128 + k] * inv
                  : (k == 128) ? (b2[co] - m2[co] * inv) : 0.0f;
        wsh[OFF_W2 + i] = (_Float16)val;
    } else if (idx < 13824) {            // W3 [32][80]
        int i = idx - 11264;
        int co = i / S3, k = i - co * S3;
        float inv = g3[co] / sqrtf(v3[co] + EPS);
        float val = (k < 64) ? w3[co * 64 + k] * inv
                  : (k == 64) ? (b3[co] - m3[co] * inv) : 0.0f;
        wsh[OFF_W3 + i] = (_Float16)val;
    } else if (idx < F16_TOTAL) {        // W4 [32][48], rows 16-31 zero (M pad)
        int i = idx - 13824;
        int co = i / S4, k = i - co * S4;
        float val = 0.0f;
        if (co < 16) {
            float inv = g4[co] / sqrtf(v4[co] + EPS);
            val = (k < 32) ? w4[co * 32 + k] * inv
                : (k == 32) ? (b4[co] - m4[co] * inv) : 0.0f;
        }
        wsh[OFF_W4 + i] = (_Float16)val;
    } else if (idx < F16_TOTAL + 16) {   // wh (f32)
        wsf[OFF_WH_F32 + (idx - F16_TOTAL)] = wh[idx - F16_TOTAL];
    } else if (idx == F16_TOTAL + 16) {  // bh
        wsf[OFF_BH_F32] = bh[0];
    }
}

// relu + f16-pack (RNE) + cross-half exchange: one 32-row D tile -> 2 B fragments.
// Convention-free: uses __shfl_xor (guaranteed semantics), not permlane.
//
// Lane half h owns D rows (r&3)+8*(r>>2)+4h (HW-verified C/D map), so packed
// words are p[0]={0,1}+4h, p[1]={2,3}+4h, p[2]={8,9}+4h, p[3]={10,11}+4h,
// p[4..7] = same +16. Fragment slot (g,e) of K-block ks must hold channel
// 16ks+8g+e (same mu-map as the A-side packing; mu cancels in the MFMA).
//   lo lane (g=0) needs: own p[b+0],p[b+1] (ch 0-3) + hi's p[b+0],p[b+1] (ch 4-7)
//   hi lane (g=1) needs: lo's p[b+2],p[b+3] (ch 8-11) + own p[b+2],p[b+3] (ch 12-15)
// Each lane pre-selects the word its partner needs, then one shfl_xor(32) per word-pair.
__device__ inline void repack_tile(const f32x16 d, bool hi, half8* out2) {
    unsigned p[8];
    #pragma unroll
    for (int w = 0; w < 8; ++w) {
        half2t t;
        t.x = (_Float16)fmaxf(d[2 * w], 0.0f);
        t.y = (_Float16)fmaxf(d[2 * w + 1], 0.0f);
        p[w] = __builtin_bit_cast(unsigned, t);
    }
    #pragma unroll
    for (int ks = 0; ks < 2; ++ks) {
        const int b = 4 * ks;
        // send what the partner needs: lo sends p[b+2],p[b+3]; hi sends p[b+0],p[b+1]
        unsigned t0 = hi ? p[b + 0] : p[b + 2];
        unsigned t1 = hi ? p[b + 1] : p[b + 3];
        unsigned r0 = (unsigned)__shfl_xor((int)t0, 32, 64);  // lo recv hi p[b+0]; hi recv lo p[b+2]
        unsigned r1 = (unsigned)__shfl_xor((int)t1, 32, 64);  // lo recv hi p[b+1]; hi recv lo p[b+3]
        uint4t f;
        f.x = hi ? r0 : p[b + 0];   // ch 8g+0,8g+1
        f.y = hi ? r1 : p[b + 1];   // ch 8g+2,8g+3
        f.z = hi ? p[b + 2] : r0;   // ch 8g+4,8g+5
        f.w = hi ? p[b + 3] : r1;   // ch 8g+6,8g+7
        out2[ks] = __builtin_bit_cast(half8, f);
    }
}

__device__ inline f32x16 zero16() {
    f32x16 z;
    #pragma unroll
    for (int i = 0; i < 16; ++i) z[i] = 0.0f;
    return z;
}

// -------------- fused MLP (all-MFMA, pixels on columns) --------------
__global__ __launch_bounds__(256, 2) void mlp_mfma(
    const float* __restrict__ x, const void* __restrict__ wsv, float* __restrict__ out)
{
    const _Float16* wsh = (const _Float16*)wsv;
    const float*    wsf = (const float*)wsv;

    const int tid  = threadIdx.x;
    const int l    = tid & 63;
    const int g    = l >> 5;            // lane half (0/1)
    const bool hi  = (g != 0);
    const int col  = l & 31;            // pixel column within tile
    const int wave = tid >> 6;
    const long wgid = (long)blockIdx.x * 4 + wave;

    // ---- prologue: persist all folded weight fragments in VGPRs ----
    half8 A1[4], A2[2][9], A3[5], A4[3];
    #pragma unroll
    for (int mt = 0; mt < 4; ++mt)
        A1[mt] = *(const half8*)(wsh + OFF_W1 + (col + 32 * mt) * S1 + 8 * g);
    #pragma unroll
    for (int mt = 0; mt < 2; ++mt)
        #pragma unroll
        for (int ks = 0; ks < 9; ++ks)
            A2[mt][ks] = *(const half8*)(wsh + OFF_W2 + (col + 32 * mt) * S2 + 16 * ks + 8 * g);
    #pragma unroll
    for (int ks = 0; ks < 5; ++ks)
        A3[ks] = *(const half8*)(wsh + OFF_W3 + col * S3 + 16 * ks + 8 * g);
    #pragma unroll
    for (int ks = 0; ks < 3; ++ks)
        A4[ks] = *(const half8*)(wsh + OFF_W4 + col * S4 + 16 * ks + 8 * g);

    float whv[8];
    #pragma unroll
    for (int e = 0; e < 8; ++e)
        whv[e] = wsf[OFF_WH_F32 + ((e & 3) + 8 * (e >> 2) + 4 * g)];
    const float bhv = wsf[OFF_BH_F32];

    // constant B fragment supplying 1.0 at the bias K-slot (k = first col of block)
    uint4t bbu; bbu.x = (g == 0) ? 0x00003C00u : 0u; bbu.y = 0u; bbu.z = 0u; bbu.w = 0u;
    const half8 Bbias = __builtin_bit_cast(half8, bbu);

    // ---- main loop: 32 pixels per iteration ----
    float xc0, xc1, xc2;
    {
        long q = wgid * ITERS * 32 + col;
        int n = (int)(q >> 18); int p = (int)(q & (HWSZ - 1));
        const float* xb = x + (size_t)n * 3 * HWSZ + p;
        xc0 = xb[0]; xc1 = xb[HWSZ]; xc2 = xb[2 * HWSZ];
    }

    for (int it = 0; it < ITERS; ++it) {
        const long q = (wgid * ITERS + it) * 32 + col;

        // B1 fragment: k = {x0, x1, x2, 1(bias), 0...}; upper lane-half all zero
        half2t t01; t01.x = (_Float16)xc0; t01.y = (_Float16)xc1;
        half2t t23; t23.x = (_Float16)xc2; t23.y = (_Float16)1.0f;
        unsigned bw0 = __builtin_bit_cast(unsigned, t01);
        unsigned bw1 = __builtin_bit_cast(unsigned, t23);
        uint4t b1u; b1u.x = (g == 0) ? bw0 : 0u; b1u.y = (g == 0) ? bw1 : 0u; b1u.z = 0u; b1u.w = 0u;
        const half8 B1 = __builtin_bit_cast(half8, b1u);

        // prefetch next iteration's pixels (overlaps the compute below)
        if (it + 1 < ITERS) {
            long q2 = q + 32;
            int n2 = (int)(q2 >> 18); int p2 = (int)(q2 & (HWSZ - 1));
            const float* xb2 = x + (size_t)n2 * 3 * HWSZ + p2;
            xc0 = xb2[0]; xc1 = xb2[HWSZ]; xc2 = xb2[2 * HWSZ];
        }

        // ---- L1 (3->128, K=16 padded, bias in K) + repack -> B2 ----
        half8 B2[8];
        #pragma unroll
        for (int h = 0; h < 2; ++h) {
            f32x16 a0 = MFMA32(A1[2 * h + 0], B1, zero16());
            f32x16 a1 = MFMA32(A1[2 * h + 1], B1, zero16());
            repack_tile(a0, hi, &B2[4 * h + 0]);
            repack_tile(a1, hi, &B2[4 * h + 2]);
        }

        // ---- L2 (128->64, K=144 incl bias) ----
        f32x16 c20 = zero16(), c21 = zero16();
        #pragma unroll
        for (int ks = 0; ks < 8; ++ks) {
            c20 = MFMA32(A2[0][ks], B2[ks], c20);
            c21 = MFMA32(A2[1][ks], B2[ks], c21);
        }
        c20 = MFMA32(A2[0][8], Bbias, c20);
        c21 = MFMA32(A2[1][8], Bbias, c21);

        // ---- repack -> B3; L3 (64->32, K=80 incl bias) ----
        half8 B3[4];
        repack_tile(c20, hi, &B3[0]);
        repack_tile(c21, hi, &B3[2]);
        f32x16 c3 = zero16();
        #pragma unroll
        for (int ks = 0; ks < 4; ++ks) c3 = MFMA32(A3[ks], B3[ks], c3);
        c3 = MFMA32(A3[4], Bbias, c3);

        // ---- repack -> B4; L4 (32->16, K=48 incl bias, M padded) ----
        half8 B4[2];
        repack_tile(c3, hi, &B4[0]);
        f32x16 c4 = zero16();
        c4 = MFMA32(A4[0], B4[0], c4);
        c4 = MFMA32(A4[1], B4[1], c4);
        c4 = MFMA32(A4[2], Bbias, c4);

        // ---- head: out = sum_ch wh[ch]*relu(h4[ch]) + bh (rows 0-15 live in regs 0-7) ----
        float s = 0.0f;
        #pragma unroll
        for (int e = 0; e < 8; ++e) s = fmaf(whv[e], fmaxf(c4[e], 0.0f), s);
        float partner = __shfl_xor(s, 32, 64);   // guaranteed-semantics cross-half add
        float val = s + partner + bhv;
        if (l < 32) out[q] = val;
    }
}

extern "C" void kernel_launch(void* const* d_in, const int* in_sizes, int n_in,
                              void* d_out, int out_size, void* d_ws, size_t ws_size,
                              hipStream_t stream) {
    const float* x  = (const float*)d_in[0];
    const float* w1 = (const float*)d_in[1];
    const float* g1 = (const float*)d_in[2];
    const float* b1 = (const float*)d_in[3];
    const float* m1 = (const float*)d_in[4];
    const float* v1 = (const float*)d_in[5];
    const float* w2 = (const float*)d_in[6];
    const float* g2 = (const float*)d_in[7];
    const float* b2 = (const float*)d_in[8];
    const float* m2 = (const float*)d_in[9];
    const float* v2 = (const float*)d_in[10];
    const float* w3 = (const float*)d_in[11];
    const float* g3 = (const float*)d_in[12];
    const float* b3 = (const float*)d_in[13];
    const float* m3 = (const float*)d_in[14];
    const float* v3 = (const float*)d_in[15];
    const float* w4 = (const float*)d_in[16];
    const float* g4 = (const float*)d_in[17];
    const float* b4 = (const float*)d_in[18];
    const float* m4 = (const float*)d_in[19];
    const float* v4 = (const float*)d_in[20];
    const float* wh = (const float*)d_in[21];
    const float* bh = (const float*)d_in[22];

    fold_weights<<<64, 256, 0, stream>>>(w1, g1, b1, m1, v1,
                                         w2, g2, b2, m2, v2,
                                         w3, g3, b3, m3, v3,
                                         w4, g4, b4, m4, v4,
                                         wh, bh, d_ws);

    mlp_mfma<<<GRID, 256, 0, stream>>>(x, d_ws, (float*)d_out);
}